// Round 10
// baseline (216.625 us; speedup 1.0000x reference)
//
#include <hip/hip_runtime.h>

#define TT 25000
#define BB 2
#define CC 128
#define NN (BB*TT)   // 50000 nodes
#define NB ((NN + 255) / 256)  // 196 scan blocks

typedef __attribute__((ext_vector_type(8))) short bf16x8;
typedef __attribute__((ext_vector_type(4))) float f32x4;

__device__ inline unsigned short f2bf(float f) {
    unsigned int u = __float_as_uint(f);
    u += 0x7FFF + ((u >> 16) & 1);          // round-to-nearest-even
    return (unsigned short)(u >> 16);
}
__device__ inline float bfhi(unsigned int v) { return __uint_as_float(v << 16); }
__device__ inline float bflo(unsigned int v) { return __uint_as_float(v & 0xFFFF0000u); }

// ---------------- degree count + per-edge sequence number ----------------
__global__ __launch_bounds__(256) void k_deg(const int* __restrict__ dst, int E,
                                             int* __restrict__ deg,
                                             int* __restrict__ eseq) {
    int i0 = blockIdx.x * 512 + threadIdx.x;
    int i1 = i0 + 256;
    int d0 = 0, d1 = 0;
    bool ok0 = (i0 < E), ok1 = (i1 < E);
    if (ok0) d0 = dst[i0];
    if (ok1) d1 = dst[i1];
    if (ok0) eseq[i0] = atomicAdd(&deg[d0], 1);
    if (ok1) eseq[i1] = atomicAdd(&deg[d1], 1);
}

// ---------------- scan (single pass): block prefix by redundant reduce ----------------
__global__ __launch_bounds__(256) void k_scan(const int* __restrict__ deg,
                                              int* __restrict__ off,
                                              float* __restrict__ dinv) {
    __shared__ int part[256];
    int tid = threadIdx.x;
    int bi = blockIdx.x;
    int i = bi * 256 + tid;

    int s = 0;
    for (int j = tid; j < bi * 256; j += 256) s += deg[j];
    part[tid] = s;
    __syncthreads();
#pragma unroll
    for (int o = 128; o > 0; o >>= 1) {
        if (tid < o) part[tid] += part[tid + o];
        __syncthreads();
    }
    int base = part[0];
    __syncthreads();

    int v = (i < NN) ? deg[i] : 0;
    part[tid] = v;
    __syncthreads();
    for (int o = 1; o < 256; o <<= 1) {
        int u = (tid >= o) ? part[tid - o] : 0;
        __syncthreads();
        part[tid] += u;
        __syncthreads();
    }
    int incl = part[tid];
    if (i < NN) {
        off[i]  = base + incl - v;                  // exclusive
        dinv[i] = rsqrtf((float)(v + 1));
    }
    if (i == NN - 1) off[NN] = base + incl;         // == E
}

// ---------------- CSR fill: atomic-free scatter ----------------
__global__ __launch_bounds__(256) void k_fill(const int* __restrict__ src,
                                              const int* __restrict__ dst, int E,
                                              const int* __restrict__ off,
                                              const int* __restrict__ eseq,
                                              int* __restrict__ csr_src) {
    int i = blockIdx.x * blockDim.x + threadIdx.x;
    if (i < E) {
        int d = dst[i];
        csr_src[off[d] + eseq[i]] = src[i];
    }
}

// ---------------- MFMA GEMM: 64 nodes x 128 oc per block, bf16 in/out ----------------
// h'[n][oc] = dinv[n] * sum_c x[n][c] * W[c][oc], stored bf16.
// Fragment layouts (gfx950 mfma_f32_16x16x32_bf16, HW-verified maps):
//   A: lane(m=l&15, q=l>>4) holds A[m][q*8+j]      (8 bf16, one b128)
//   B: lane(n=l&15, q=l>>4) holds B[q*8+j][n]
//   D: lane(col=l&15), row = (l>>4)*4 + reg
__global__ __launch_bounds__(256) void k_gemm(const float* __restrict__ x,
                                              const float* __restrict__ W,
                                              const float* __restrict__ dinv,
                                              unsigned short* __restrict__ h) {
    __shared__ __align__(16) unsigned short a_lds[4][4][64][8];  // [mt][kk][lane][j] 16 KB
    __shared__ __align__(16) unsigned short b_lds[8][4][64][8];  // [nt][kk][lane][j] 32 KB
    int tid = threadIdx.x;
    int n0 = blockIdx.x * 64;

    // ---- stage A (x -> bf16, fragment order) ----
    {
        int m = tid & 63;
        int n = n0 + m;
        bool ok = (n < NN);
        int b = 0, t = 0;
        if (ok) { b = n / TT; t = n - b * TT; }
        const float* xp = x + ((size_t)b * CC) * TT + t;
        int mt = m >> 4, lm = m & 15;
#pragma unroll
        for (int p = 0; p < 4; ++p) {
            int kg = (tid >> 6) + p * 4;            // 0..15, wave-uniform
            unsigned short tmp[8];
#pragma unroll
            for (int j = 0; j < 8; ++j) {
                float v = ok ? xp[(size_t)(kg * 8 + j) * TT] : 0.f;
                tmp[j] = f2bf(v);
            }
            int kk = kg >> 2, q = kg & 3;
            *(bf16x8*)&a_lds[mt][kk][lm | (q << 4)][0] = *(bf16x8*)tmp;
        }
    }
    // ---- stage B (W -> bf16, fragment order) ----
    {
        int nc = tid & 127;
        int nt = nc >> 4, ln = nc & 15;
#pragma unroll
        for (int p = 0; p < 8; ++p) {
            int kg = (tid >> 7) + p * 2;            // 0..15
            unsigned short tmp[8];
#pragma unroll
            for (int j = 0; j < 8; ++j)
                tmp[j] = f2bf(W[(kg * 8 + j) * CC + nc]);
            int kk = kg >> 2, q = kg & 3;
            *(bf16x8*)&b_lds[nt][kk][ln | (q << 4)][0] = *(bf16x8*)tmp;
        }
    }
    __syncthreads();

    int lane = tid & 63;
    int w = tid >> 6;                               // wave = m-tile
    f32x4 acc[8];
#pragma unroll
    for (int nt = 0; nt < 8; ++nt) acc[nt] = (f32x4){0.f, 0.f, 0.f, 0.f};
#pragma unroll
    for (int kk = 0; kk < 4; ++kk) {
        bf16x8 a = *(const bf16x8*)&a_lds[w][kk][lane][0];
#pragma unroll
        for (int nt = 0; nt < 8; ++nt) {
            bf16x8 bb = *(const bf16x8*)&b_lds[nt][kk][lane][0];
            acc[nt] = __builtin_amdgcn_mfma_f32_16x16x32_bf16(a, bb, acc[nt], 0, 0, 0);
        }
    }

    // ---- epilogue: scale by dinv, bf16, store ----
    int q = lane >> 4, col = lane & 15;
    int nodebase = n0 + w * 16 + q * 4;
    float di[4];
#pragma unroll
    for (int r = 0; r < 4; ++r) {
        int nn = nodebase + r;
        di[r] = (nn < NN) ? dinv[nn] : 0.f;
    }
#pragma unroll
    for (int nt = 0; nt < 8; ++nt) {
#pragma unroll
        for (int r = 0; r < 4; ++r) {
            int nn = nodebase + r;
            if (nn < NN)
                h[(size_t)nn * CC + nt * 16 + col] = f2bf(di[r] * acc[nt][r]);
        }
    }
}

// ---------------- aggregation: one wave per node; vectorized index fetch ----------------
__global__ __launch_bounds__(256) void k_agg(const unsigned int* __restrict__ hb,
                                             const int* __restrict__ off,
                                             const int* __restrict__ csr_src,
                                             const float* __restrict__ dinv,
                                             const float* __restrict__ bias,
                                             float* __restrict__ agg) {
    int lane = threadIdx.x & 63;
    int w    = threadIdx.x >> 6;
    int n    = blockIdx.x * 4 + w;
    if (n >= NN) return;
    float ax = 0.f, ay = 0.f;
    int e0 = off[n], e1 = off[n + 1];

    for (int c0 = e0; c0 < e1; c0 += 64) {
        int cnt = e1 - c0; if (cnt > 64) cnt = 64;
        int li = lane < cnt ? lane : cnt - 1;
        int iv = csr_src[c0 + li];                  // 64 indices, one coalesced load
        int j = 0;
        for (; j + 16 <= cnt; j += 16) {
            int s[16];
#pragma unroll
            for (int u = 0; u < 16; ++u) s[u] = __shfl(iv, j + u, 64);
            unsigned int v[16];
#pragma unroll
            for (int u = 0; u < 16; ++u) v[u] = hb[(size_t)s[u] * 64 + lane];
#pragma unroll
            for (int u = 0; u < 16; ++u) { ax += bfhi(v[u]); ay += bflo(v[u]); }
        }
        for (; j + 4 <= cnt; j += 4) {
            int s[4];
#pragma unroll
            for (int u = 0; u < 4; ++u) s[u] = __shfl(iv, j + u, 64);
            unsigned int v[4];
#pragma unroll
            for (int u = 0; u < 4; ++u) v[u] = hb[(size_t)s[u] * 64 + lane];
#pragma unroll
            for (int u = 0; u < 4; ++u) { ax += bfhi(v[u]); ay += bflo(v[u]); }
        }
        for (; j < cnt; ++j) {
            int s = __shfl(iv, j, 64);
            unsigned int v = hb[(size_t)s * 64 + lane];
            ax += bfhi(v); ay += bflo(v);
        }
    }

    unsigned int hv = hb[(size_t)n * 64 + lane];    // self loop
    ax += bfhi(hv);
    ay += bflo(hv);
    float di = dinv[n];
    const float2* b2 = (const float2*)bias;
    float2 bb = b2[lane];
    float rx = fmaxf(fmaf(di, ax, bb.x), 0.f);
    float ry = fmaxf(fmaf(di, ay, bb.y), 0.f);
    ((float2*)agg)[(size_t)n * 64 + lane] = make_float2(rx, ry);
}

// ---------------- transpose [n][oc] -> [b][oc][t] ----------------
__global__ void k_trans(const float* __restrict__ agg, float* __restrict__ out) {
    __shared__ float tile[32][33];
    int t0 = blockIdx.x * 32;
    int o0 = blockIdx.y * 32;
    int b  = blockIdx.z;
    int tx = threadIdx.x, ty = threadIdx.y;         // 32 x 8
#pragma unroll
    for (int i = 0; i < 4; ++i) {
        int t = t0 + ty + i * 8;
        if (t < TT) tile[ty + i * 8][tx] = agg[(size_t)(b * TT + t) * CC + o0 + tx];
    }
    __syncthreads();
#pragma unroll
    for (int i = 0; i < 4; ++i) {
        int t  = t0 + tx;
        int oc = o0 + ty + i * 8;
        if (t < TT) out[((size_t)b * CC + oc) * TT + t] = tile[tx][ty + i * 8];
    }
}

extern "C" void kernel_launch(void* const* d_in, const int* in_sizes, int n_in,
                              void* d_out, int out_size, void* d_ws, size_t ws_size,
                              hipStream_t stream) {
    const float* x    = (const float*)d_in[0];
    const float* W    = (const float*)d_in[1];
    const float* bias = (const float*)d_in[2];
    const int*   ei   = (const int*)d_in[3];
    int E = in_sizes[3] / 2;
    const int* src = ei;
    const int* dst = ei + E;
    float* out = (float*)d_out;

    char* ws = (char*)d_ws;
    size_t o = 0;
    unsigned short* h = (unsigned short*)(ws + o); o += (size_t)NN * CC * 2;  // 12.8 MB
    float* agg  = (float*)(ws + o); o += (size_t)NN * CC * 4;                 // 25.6 MB
    int*   deg  = (int*)  (ws + o); o += (size_t)NN * 4;
    float* dinv = (float*)(ws + o); o += (size_t)NN * 4;
    int*   off  = (int*)  (ws + o); o += (size_t)(NN + 1) * 4 + 12;
    int*   eseq = (int*)  (ws + o); o += (size_t)E * 4;
    int*   csrs = (int*)  (ws + o); o += (size_t)E * 4;

    hipMemsetAsync(deg, 0, (size_t)NN * 4, stream);

    k_deg  <<<(E + 511) / 512, 256, 0, stream>>>(dst, E, deg, eseq);
    k_scan <<<NB, 256, 0, stream>>>(deg, off, dinv);
    k_fill <<<(E + 255) / 256, 256, 0, stream>>>(src, dst, E, off, eseq, csrs);
    k_gemm <<<(NN + 63) / 64, 256, 0, stream>>>(x, W, dinv, h);
    k_agg  <<<(NN + 3) / 4, 256, 0, stream>>>((const unsigned int*)h, off, csrs, dinv, bias, agg);
    dim3 tg((TT + 31) / 32, CC / 32, BB);
    k_trans<<<tg, dim3(32, 8), 0, stream>>>(agg, out);
}

// Round 11
// 196.605 us; speedup vs baseline: 1.1018x; 1.1018x over previous
//
#include <hip/hip_runtime.h>

#define TT 25000
#define BB 2
#define CC 128
#define NN (BB*TT)   // 50000 nodes
#define NB ((NN + 255) / 256)  // 196 scan blocks

typedef __attribute__((ext_vector_type(8))) short bf16x8;
typedef __attribute__((ext_vector_type(4))) float f32x4;

__device__ inline unsigned short f2bf(float f) {
    unsigned int u = __float_as_uint(f);
    u += 0x7FFF + ((u >> 16) & 1);          // round-to-nearest-even
    return (unsigned short)(u >> 16);
}
__device__ inline float bfhi(unsigned int v) { return __uint_as_float(v << 16); }
__device__ inline float bflo(unsigned int v) { return __uint_as_float(v & 0xFFFF0000u); }

// ---------------- degree count + per-edge sequence number ----------------
__global__ __launch_bounds__(256) void k_deg(const int* __restrict__ dst, int E,
                                             int* __restrict__ deg,
                                             int* __restrict__ eseq) {
    int i0 = blockIdx.x * 512 + threadIdx.x;
    int i1 = i0 + 256;
    int d0 = 0, d1 = 0;
    bool ok0 = (i0 < E), ok1 = (i1 < E);
    if (ok0) d0 = dst[i0];
    if (ok1) d1 = dst[i1];
    if (ok0) eseq[i0] = atomicAdd(&deg[d0], 1);
    if (ok1) eseq[i1] = atomicAdd(&deg[d1], 1);
}

// ---------------- scan pass 1: per-block sums ----------------
__global__ __launch_bounds__(256) void k_bsum(const int* __restrict__ deg,
                                              int* __restrict__ bsum) {
    __shared__ int red[256];
    int tid = threadIdx.x;
    int i = blockIdx.x * 256 + tid;
    red[tid] = (i < NN) ? deg[i] : 0;
    __syncthreads();
#pragma unroll
    for (int o = 128; o > 0; o >>= 1) {
        if (tid < o) red[tid] += red[tid + o];
        __syncthreads();
    }
    if (tid == 0) bsum[blockIdx.x] = red[0];
}

// ---------------- scan pass 2: block prefix + local scan + dinv ----------------
__global__ __launch_bounds__(256) void k_scan2(const int* __restrict__ deg,
                                               const int* __restrict__ bsum,
                                               int* __restrict__ off,
                                               float* __restrict__ dinv) {
    __shared__ int part[256];
    __shared__ int bpref;
    int tid = threadIdx.x;
    int i = blockIdx.x * 256 + tid;

    part[tid] = (tid < NB && tid < blockIdx.x) ? bsum[tid] : 0;
    __syncthreads();
#pragma unroll
    for (int o = 128; o > 0; o >>= 1) {
        if (tid < o) part[tid] += part[tid + o];
        __syncthreads();
    }
    if (tid == 0) bpref = part[0];
    __syncthreads();
    int base = bpref;
    __syncthreads();

    int v = (i < NN) ? deg[i] : 0;
    part[tid] = v;
    __syncthreads();
#pragma unroll
    for (int o = 1; o < 256; o <<= 1) {
        int u = (tid >= o) ? part[tid - o] : 0;
        __syncthreads();
        part[tid] += u;
        __syncthreads();
    }
    int incl = part[tid];
    if (i < NN) {
        off[i]  = base + incl - v;                  // exclusive
        dinv[i] = rsqrtf((float)(v + 1));
    }
    if (i == NN - 1) off[NN] = base + incl;         // == E
}

// ---------------- CSR fill: atomic-free scatter ----------------
__global__ __launch_bounds__(256) void k_fill(const int* __restrict__ src,
                                              const int* __restrict__ dst, int E,
                                              const int* __restrict__ off,
                                              const int* __restrict__ eseq,
                                              int* __restrict__ csr_src) {
    int i = blockIdx.x * blockDim.x + threadIdx.x;
    if (i < E) {
        int d = dst[i];
        csr_src[off[d] + eseq[i]] = src[i];
    }
}

// ---------------- MFMA GEMM: 64 nodes x 128 oc per block, bf16 in/out ----------------
// h'[n][oc] = dinv[n] * sum_c x[n][c] * W[c][oc], stored bf16.
__global__ __launch_bounds__(256) void k_gemm(const float* __restrict__ x,
                                              const float* __restrict__ W,
                                              const float* __restrict__ dinv,
                                              unsigned short* __restrict__ h) {
    __shared__ __align__(16) unsigned short a_lds[4][4][64][8];  // [mt][kk][lane][j] 16 KB
    __shared__ __align__(16) unsigned short b_lds[8][4][64][8];  // [nt][kk][lane][j] 32 KB
    int tid = threadIdx.x;
    int n0 = blockIdx.x * 64;

    // ---- stage A (x -> bf16, fragment order) ----
    {
        int m = tid & 63;
        int n = n0 + m;
        bool ok = (n < NN);
        int b = 0, t = 0;
        if (ok) { b = n / TT; t = n - b * TT; }
        const float* xp = x + ((size_t)b * CC) * TT + t;
        int mt = m >> 4, lm = m & 15;
#pragma unroll
        for (int p = 0; p < 4; ++p) {
            int kg = (tid >> 6) + p * 4;            // 0..15, wave-uniform
            unsigned short tmp[8];
#pragma unroll
            for (int j = 0; j < 8; ++j) {
                float v = ok ? xp[(size_t)(kg * 8 + j) * TT] : 0.f;
                tmp[j] = f2bf(v);
            }
            int kk = kg >> 2, q = kg & 3;
            *(bf16x8*)&a_lds[mt][kk][lm | (q << 4)][0] = *(bf16x8*)tmp;
        }
    }
    // ---- stage B (W -> bf16, fragment order) ----
    {
        int nc = tid & 127;
        int nt = nc >> 4, ln = nc & 15;
#pragma unroll
        for (int p = 0; p < 8; ++p) {
            int kg = (tid >> 7) + p * 2;            // 0..15
            unsigned short tmp[8];
#pragma unroll
            for (int j = 0; j < 8; ++j)
                tmp[j] = f2bf(W[(kg * 8 + j) * CC + nc]);
            int kk = kg >> 2, q = kg & 3;
            *(bf16x8*)&b_lds[nt][kk][ln | (q << 4)][0] = *(bf16x8*)tmp;
        }
    }
    __syncthreads();

    int lane = tid & 63;
    int w = tid >> 6;                               // wave = m-tile
    f32x4 acc[8];
#pragma unroll
    for (int nt = 0; nt < 8; ++nt) acc[nt] = (f32x4){0.f, 0.f, 0.f, 0.f};
#pragma unroll
    for (int kk = 0; kk < 4; ++kk) {
        bf16x8 a = *(const bf16x8*)&a_lds[w][kk][lane][0];
#pragma unroll
        for (int nt = 0; nt < 8; ++nt) {
            bf16x8 bb = *(const bf16x8*)&b_lds[nt][kk][lane][0];
            acc[nt] = __builtin_amdgcn_mfma_f32_16x16x32_bf16(a, bb, acc[nt], 0, 0, 0);
        }
    }

    // ---- epilogue: scale by dinv, bf16, store ----
    int q = lane >> 4, col = lane & 15;
    int nodebase = n0 + w * 16 + q * 4;
    float di[4];
#pragma unroll
    for (int r = 0; r < 4; ++r) {
        int nn = nodebase + r;
        di[r] = (nn < NN) ? dinv[nn] : 0.f;
    }
#pragma unroll
    for (int nt = 0; nt < 8; ++nt) {
#pragma unroll
        for (int r = 0; r < 4; ++r) {
            int nn = nodebase + r;
            if (nn < NN)
                h[(size_t)nn * CC + nt * 16 + col] = f2bf(di[r] * acc[nt][r]);
        }
    }
}

// ---------------- aggregation: one wave per node; vectorized index fetch ----------------
__global__ __launch_bounds__(256) void k_agg(const unsigned int* __restrict__ hb,
                                             const int* __restrict__ off,
                                             const int* __restrict__ csr_src,
                                             const float* __restrict__ dinv,
                                             const float* __restrict__ bias,
                                             float* __restrict__ agg) {
    int lane = threadIdx.x & 63;
    int w    = threadIdx.x >> 6;
    int n    = blockIdx.x * 4 + w;
    if (n >= NN) return;
    float ax = 0.f, ay = 0.f;
    int e0 = off[n], e1 = off[n + 1];

    for (int c0 = e0; c0 < e1; c0 += 64) {
        int cnt = e1 - c0; if (cnt > 64) cnt = 64;
        int li = lane < cnt ? lane : cnt - 1;
        int iv = csr_src[c0 + li];                  // 64 indices, one coalesced load
        int j = 0;
        for (; j + 16 <= cnt; j += 16) {
            int s[16];
#pragma unroll
            for (int u = 0; u < 16; ++u) s[u] = __shfl(iv, j + u, 64);
            unsigned int v[16];
#pragma unroll
            for (int u = 0; u < 16; ++u) v[u] = hb[(size_t)s[u] * 64 + lane];
#pragma unroll
            for (int u = 0; u < 16; ++u) { ax += bfhi(v[u]); ay += bflo(v[u]); }
        }
        for (; j + 4 <= cnt; j += 4) {
            int s[4];
#pragma unroll
            for (int u = 0; u < 4; ++u) s[u] = __shfl(iv, j + u, 64);
            unsigned int v[4];
#pragma unroll
            for (int u = 0; u < 4; ++u) v[u] = hb[(size_t)s[u] * 64 + lane];
#pragma unroll
            for (int u = 0; u < 4; ++u) { ax += bfhi(v[u]); ay += bflo(v[u]); }
        }
        for (; j < cnt; ++j) {
            int s = __shfl(iv, j, 64);
            unsigned int v = hb[(size_t)s * 64 + lane];
            ax += bfhi(v); ay += bflo(v);
        }
    }

    unsigned int hv = hb[(size_t)n * 64 + lane];    // self loop
    ax += bfhi(hv);
    ay += bflo(hv);
    float di = dinv[n];
    const float2* b2 = (const float2*)bias;
    float2 bb = b2[lane];
    float rx = fmaxf(fmaf(di, ax, bb.x), 0.f);
    float ry = fmaxf(fmaf(di, ay, bb.y), 0.f);
    ((float2*)agg)[(size_t)n * 64 + lane] = make_float2(rx, ry);
}

// ---------------- transpose [n][oc] -> [b][oc][t] ----------------
__global__ void k_trans(const float* __restrict__ agg, float* __restrict__ out) {
    __shared__ float tile[32][33];
    int t0 = blockIdx.x * 32;
    int o0 = blockIdx.y * 32;
    int b  = blockIdx.z;
    int tx = threadIdx.x, ty = threadIdx.y;         // 32 x 8
#pragma unroll
    for (int i = 0; i < 4; ++i) {
        int t = t0 + ty + i * 8;
        if (t < TT) tile[ty + i * 8][tx] = agg[(size_t)(b * TT + t) * CC + o0 + tx];
    }
    __syncthreads();
#pragma unroll
    for (int i = 0; i < 4; ++i) {
        int t  = t0 + tx;
        int oc = o0 + ty + i * 8;
        if (t < TT) out[((size_t)b * CC + oc) * TT + t] = tile[tx][ty + i * 8];
    }
}

extern "C" void kernel_launch(void* const* d_in, const int* in_sizes, int n_in,
                              void* d_out, int out_size, void* d_ws, size_t ws_size,
                              hipStream_t stream) {
    const float* x    = (const float*)d_in[0];
    const float* W    = (const float*)d_in[1];
    const float* bias = (const float*)d_in[2];
    const int*   ei   = (const int*)d_in[3];
    int E = in_sizes[3] / 2;
    const int* src = ei;
    const int* dst = ei + E;
    float* out = (float*)d_out;

    char* ws = (char*)d_ws;
    size_t o = 0;
    unsigned short* h = (unsigned short*)(ws + o); o += (size_t)NN * CC * 2;  // 12.8 MB
    float* agg  = (float*)(ws + o); o += (size_t)NN * CC * 4;                 // 25.6 MB
    int*   deg  = (int*)  (ws + o); o += (size_t)NN * 4;
    float* dinv = (float*)(ws + o); o += (size_t)NN * 4;
    int*   off  = (int*)  (ws + o); o += (size_t)(NN + 1) * 4 + 12;
    int*   bsum = (int*)  (ws + o); o += (size_t)((NB + 3) & ~3) * 4;
    int*   eseq = (int*)  (ws + o); o += (size_t)E * 4;
    int*   csrs = (int*)  (ws + o); o += (size_t)E * 4;

    hipMemsetAsync(deg, 0, (size_t)NN * 4, stream);

    k_deg  <<<(E + 511) / 512, 256, 0, stream>>>(dst, E, deg, eseq);
    k_bsum <<<NB, 256, 0, stream>>>(deg, bsum);
    k_scan2<<<NB, 256, 0, stream>>>(deg, bsum, off, dinv);
    k_fill <<<(E + 255) / 256, 256, 0, stream>>>(src, dst, E, off, eseq, csrs);
    k_gemm <<<(NN + 63) / 64, 256, 0, stream>>>(x, W, dinv, h);
    k_agg  <<<(NN + 3) / 4, 256, 0, stream>>>((const unsigned int*)h, off, csrs, dinv, bias, agg);
    dim3 tg((TT + 31) / 32, CC / 32, BB);
    k_trans<<<tg, dim3(32, 8), 0, stream>>>(agg, out);
}